// Round 6
// baseline (132.644 us; speedup 1.0000x reference)
//
#include <hip/hip_runtime.h>
#include <hip/hip_bf16.h>

#define N_NODES 50000
#define N_EDGES 640000
#define C 128            // IN_C == HID
#define NB 196           // dst buckets of 256 nodes (50000 <= 196*256)
#define NTILES (N_NODES / 16)                               // 3125

typedef __bf16 bf16x8 __attribute__((ext_vector_type(8)));
typedef __bf16 bf16x4 __attribute__((ext_vector_type(4)));
typedef float  f32x4  __attribute__((ext_vector_type(4)));
typedef unsigned int u32x4 __attribute__((ext_vector_type(4)));
typedef unsigned int u32x8 __attribute__((ext_vector_type(8)));

// ---- d_ws layout (byte offsets; ws is 256 MiB per the harness poison) ----
#define WS_BCNT  0          // NB ints (bucket histogram; zeroed by precomp blk0)
#define WS_BOFF  1024       // NB+1 ints (bucket offsets)
#define WS_GCUR  2048       // NB ints (partition cursors)
#define WS_OFF   3072       // N+1 ints (CSR row offsets)
#define WS_SRCS  203776     // E ints (src ids grouped by dst)
#define WS_REC   2764800    // E u32 packed records
#define WS_HDST  5325312    // N*C bf16 (Hdst + bias)
#define WS_HSRC  18125824   // N*C bf16
// total ~30.9 MB

// XOR-swizzle for [16][128]-short LDS tiles: flip short-offset bits 3..5 with
// row&7 -> frag reads across 16 rows hit 8 distinct 16B slots (2-way = free).
__device__ __forceinline__ int swzS(int row, int soff) {
    return row * 128 + (soff ^ ((row & 7) << 3));
}
// [16][256]-short variant (node-update staging)
__device__ __forceinline__ int swz8(int row, int soff) {
    return row * 256 + (soff ^ ((row & 7) << 3));
}

// ---------------------------------------------------------------------------
// Precompute Hsrc = embed @ Wmsg[0:128]          (bf16, ws)
//            Hdst = embed @ Wmsg[128:256] + b    (bf16, ws)
// Runs FIRST; block 0 also zeroes bcnt (replaces the pathological tiny fill).
// ---------------------------------------------------------------------------
__global__ __launch_bounds__(512) void precomp_kernel(
    const float* __restrict__ embed, const float* __restrict__ Wmsg,
    const float* __restrict__ bmsg,  __bf16* __restrict__ Hsrc,
    __bf16* __restrict__ Hdst, int* __restrict__ bcnt)
{
    __shared__ short lds[16 * 128];

    const int t = threadIdx.x, lane = t & 63, wave = t >> 6;
    const int chbase = wave * 16, q = lane >> 4, nr = lane & 15;
    const int ch = chbase + nr;

    if (blockIdx.x == 0 && t < NB) bcnt[t] = 0;

    bf16x8 aS[4], aD[4];
    #pragma unroll
    for (int ks = 0; ks < 4; ++ks)
        #pragma unroll
        for (int i = 0; i < 8; ++i) {
            const int k = ks * 32 + q * 8 + i;
            aS[ks][i] = (__bf16)Wmsg[k * C + ch];
            aD[ks][i] = (__bf16)Wmsg[(128 + k) * C + ch];
        }
    float bias[4];
    #pragma unroll
    for (int r = 0; r < 4; ++r) bias[r] = bmsg[chbase + q * 4 + r];

    for (int nt = blockIdx.x; nt < NTILES; nt += gridDim.x) {
        const int n0 = nt * 16;
        {   // stage 16 nodes x 128 feats: f32 -> bf16 LDS
            const int row = t >> 5, seg = t & 31;
            const float4 f = *(const float4*)(embed + (long)(n0 + row) * C + seg * 4);
            bf16x4 v;
            v[0]=(__bf16)f.x; v[1]=(__bf16)f.y; v[2]=(__bf16)f.z; v[3]=(__bf16)f.w;
            *(bf16x4*)(&lds[swzS(row, seg * 4)]) = v;
        }
        __syncthreads();

        f32x4 hs = {0.f,0.f,0.f,0.f}, hd = {0.f,0.f,0.f,0.f};
        #pragma unroll
        for (int ks = 0; ks < 4; ++ks) {
            const bf16x8 b = *(const bf16x8*)(&lds[swzS(nr, ks * 32 + q * 8)]);
            hs = __builtin_amdgcn_mfma_f32_16x16x32_bf16(aS[ks], b, hs, 0, 0, 0);
            hd = __builtin_amdgcn_mfma_f32_16x16x32_bf16(aD[ks], b, hd, 0, 0, 0);
        }
        __syncthreads();

        const int node = n0 + nr;            // D: col=node, row(q*4+r)=ch
        bf16x4 vs, vd;
        #pragma unroll
        for (int r = 0; r < 4; ++r) {
            vs[r] = (__bf16)hs[r];
            vd[r] = (__bf16)(hd[r] + bias[r]);
        }
        *(bf16x4*)(Hsrc + (long)node * C + chbase + q * 4) = vs;
        *(bf16x4*)(Hdst + (long)node * C + chbase + q * 4) = vd;
    }
}

// ---------------------------------------------------------------------------
// CSR build, bucket-sorted: bcount -> bscan -> partition -> bucket_csr
// ---------------------------------------------------------------------------
__global__ __launch_bounds__(256) void bcount_kernel(
    const int* __restrict__ eidx, int* __restrict__ bcnt)
{
    __shared__ int h[NB];
    const int t = threadIdx.x;
    if (t < NB) h[t] = 0;
    __syncthreads();
    const int e0 = blockIdx.x * 1024;
    #pragma unroll
    for (int k = 0; k < 4; ++k)
        atomicAdd(&h[eidx[N_EDGES + e0 + k * 256 + t] >> 8], 1);
    __syncthreads();
    if (t < NB) atomicAdd(&bcnt[t], h[t]);
}

__global__ __launch_bounds__(256) void bscan_kernel(
    const int* __restrict__ bcnt, int* __restrict__ boff,
    int* __restrict__ gcur, int* __restrict__ off)
{
    __shared__ int lds[256];
    const int t = threadIdx.x;
    const int v = (t < NB) ? bcnt[t] : 0;
    lds[t] = v;
    __syncthreads();
    for (int s = 1; s < 256; s <<= 1) {
        const int u = (t >= s) ? lds[t - s] : 0;
        __syncthreads();
        lds[t] += u;
        __syncthreads();
    }
    const int excl = lds[t] - v;
    if (t < NB) { boff[t] = excl; gcur[t] = excl; }
    if (t == 0) { boff[NB] = N_EDGES; off[N_NODES] = N_EDGES; }
}

// bin 1024 edges/block by dst>>8 via LDS cursors; reserve per-bucket ranges
// with one global atomic per bucket per block; write packed 4B records
// (src | dstLocal<<16) in within-bucket contiguous runs.
__global__ __launch_bounds__(256) void partition_kernel(
    const int* __restrict__ eidx, int* __restrict__ gcur,
    unsigned* __restrict__ rec)
{
    __shared__ int cnt[NB];
    __shared__ int base[NB];
    const int t = threadIdx.x;
    if (t < NB) cnt[t] = 0;
    __syncthreads();
    const int e0 = blockIdx.x * 1024;
    int lrank[4], bb[4];
    unsigned prec[4];
    #pragma unroll
    for (int k = 0; k < 4; ++k) {
        const int e = e0 + k * 256 + t;
        const int r = eidx[e], c = eidx[N_EDGES + e];
        bb[k]   = c >> 8;
        prec[k] = (unsigned)r | ((unsigned)(c & 255) << 16);
        lrank[k] = atomicAdd(&cnt[bb[k]], 1);
    }
    __syncthreads();
    if (t < NB) base[t] = atomicAdd(&gcur[t], cnt[t]);
    __syncthreads();
    #pragma unroll
    for (int k = 0; k < 4; ++k)
        rec[base[bb[k]] + lrank[k]] = prec[k];
}

// one block per bucket: LDS deg-count over 256 nodes -> scan -> off[],
// then LDS-cursor scatter of src ids into the bucket's contiguous srcS range.
__global__ __launch_bounds__(256) void bucket_csr_kernel(
    const unsigned* __restrict__ rec, const int* __restrict__ boff,
    int* __restrict__ off, int* __restrict__ srcS)
{
    __shared__ int deg[256];
    __shared__ int cur[256];
    __shared__ int lds[256];
    const int t = threadIdx.x, b = blockIdx.x;
    const int r0 = boff[b], r1 = boff[b + 1], n0 = b << 8;
    deg[t] = 0;
    __syncthreads();
    for (int i = r0 + t; i < r1; i += 256)
        atomicAdd(&deg[rec[i] >> 16], 1);
    __syncthreads();
    const int v = deg[t];
    lds[t] = v;
    __syncthreads();
    for (int s = 1; s < 256; s <<= 1) {
        const int u = (t >= s) ? lds[t - s] : 0;
        __syncthreads();
        lds[t] += u;
        __syncthreads();
    }
    const int excl = r0 + lds[t] - v;
    cur[t] = excl;
    if (n0 + t < N_NODES) off[n0 + t] = excl;
    __syncthreads();
    for (int i = r0 + t; i < r1; i += 256) {
        const unsigned rc = rec[i];
        const int p = atomicAdd(&cur[rc >> 16], 1);
        srcS[p] = (int)(rc & 0xFFFFu);
    }
}

// ---------------------------------------------------------------------------
// Aggregate: one node per wave, 8 edges in flight (8 groups x 8 lanes,
// 16 ch/lane). No LDS, no barriers, no atomics. Writes `out` exactly once.
// ---------------------------------------------------------------------------
__global__ __launch_bounds__(256) void aggr_kernel(
    const __bf16* __restrict__ Hsrc, const __bf16* __restrict__ Hdst,
    const float*  __restrict__ pos,  const float* __restrict__ Wmsg,
    const int*    __restrict__ off,  const int*   __restrict__ srcS,
    float* __restrict__ out)
{
    const int lane = threadIdx.x & 63;
    const int wv   = threadIdx.x >> 6;
    const int g    = lane >> 3;          // edge sub-group 0..7
    const int c16  = (lane & 7) * 16;    // channel base (16 ch/lane)

    float w2[16], hd[16], acc[16];
    #pragma unroll
    for (int j = 0; j < 16; j += 4)
        *(f32x4*)&w2[j] = *(const f32x4*)(Wmsg + 256 * C + c16 + j);

    const int gw = blockIdx.x * 4 + wv;
    const int nw = gridDim.x * 4;
    for (int n = gw; n < N_NODES; n += nw) {
        const int o0 = off[n], o1 = off[n + 1];
        const u32x8 hdb = *(const u32x8*)(Hdst + (long)n * C + c16);
        #pragma unroll
        for (int k = 0; k < 8; ++k) {
            hd[2*k]   = __uint_as_float(hdb[k] << 16);
            hd[2*k+1] = __uint_as_float(hdb[k] & 0xffff0000u);
        }
        const float px = pos[n * 3], py = pos[n * 3 + 1], pz = pos[n * 3 + 2];
        #pragma unroll
        for (int j = 0; j < 16; ++j) acc[j] = 0.f;

        if (o1 > o0) {
            int s = srcS[min(o0 + g, o1 - 1)];
            for (int e = o0; e < o1; e += 8) {
                // issue gathers for current edge, prefetch next src id
                const float qx = pos[s * 3], qy = pos[s * 3 + 1], qz = pos[s * 3 + 2];
                const u32x8 hu = *(const u32x8*)(Hsrc + (long)s * C + c16);
                const int sn = srcS[min(e + 8 + g, o1 - 1)];
                const float dx = qx - px, dy = qy - py, dz = qz - pz;
                const float d  = dx * dx + dy * dy + dz * dz;
                const bool valid = (e + g) < o1;
                #pragma unroll
                for (int k = 0; k < 8; ++k) {
                    const float flo = __uint_as_float(hu[k] << 16);
                    const float fhi = __uint_as_float(hu[k] & 0xffff0000u);
                    const float v0 = fmaxf(flo + hd[2*k]   + d * w2[2*k],   0.f);
                    const float v1 = fmaxf(fhi + hd[2*k+1] + d * w2[2*k+1], 0.f);
                    acc[2*k]   += valid ? v0 : 0.f;
                    acc[2*k+1] += valid ? v1 : 0.f;
                }
                s = sn;
            }
        }
        #pragma unroll
        for (int j = 0; j < 16; ++j) {       // combine the 8 edge groups
            acc[j] += __shfl_xor(acc[j], 8);
            acc[j] += __shfl_xor(acc[j], 16);
            acc[j] += __shfl_xor(acc[j], 32);
        }
        if (lane < 8) {
            #pragma unroll
            for (int j = 0; j < 16; j += 4)
                *(f32x4*)(out + (long)n * C + c16 + j) = *(const f32x4*)&acc[j];
        }
    }
}

// ---------------------------------------------------------------------------
// Node update: out = embed @ W_res + relu([embed, aggr] @ W_upd + b_upd)
// (aggr lives in `out` on entry; overwritten in place, single-owner tiles)
// ---------------------------------------------------------------------------
__global__ __launch_bounds__(512) void node_upd_kernel(
    const float* __restrict__ embed, const float* __restrict__ Wres,
    const float* __restrict__ Wupd,  const float* __restrict__ bupd,
    float* __restrict__ out)
{
    __shared__ short ldsF[16 * 256];

    const int t = threadIdx.x, lane = t & 63, wave = t >> 6;
    const int chbase = wave * 16, q = lane >> 4, nr = lane & 15;

    bf16x8 aU[8], aR[4];
    {
        const int ch = chbase + nr;
        #pragma unroll
        for (int ks = 0; ks < 8; ++ks)
            #pragma unroll
            for (int i = 0; i < 8; ++i)
                aU[ks][i] = (__bf16)Wupd[(ks*32 + q*8 + i) * C + ch];
        #pragma unroll
        for (int ks = 0; ks < 4; ++ks)
            #pragma unroll
            for (int i = 0; i < 8; ++i)
                aR[ks][i] = (__bf16)Wres[(ks*32 + q*8 + i) * C + ch];
    }
    float bu[4];
    #pragma unroll
    for (int r = 0; r < 4; ++r) bu[r] = bupd[chbase + q*4 + r];

    for (int nt = blockIdx.x; nt < NTILES; nt += gridDim.x) {
        const int n0 = nt * 16;
        {   // stage [embed(f32->bf16) | aggr(f32 in out)] for 16 nodes
            const int nn = t >> 5, seg = t & 31;
            const float* base = (seg < 16) ? embed : out;
            const float* src  = base + (long)(n0 + nn) * C + (seg & 15) * 8;
            const float4 f0 = *(const float4*)src;
            const float4 f1 = *(const float4*)(src + 4);
            bf16x8 v;
            v[0]=(__bf16)f0.x; v[1]=(__bf16)f0.y; v[2]=(__bf16)f0.z; v[3]=(__bf16)f0.w;
            v[4]=(__bf16)f1.x; v[5]=(__bf16)f1.y; v[6]=(__bf16)f1.z; v[7]=(__bf16)f1.w;
            *(bf16x8*)(&ldsF[swz8(nn, seg * 8)]) = v;
        }
        __syncthreads();

        f32x4 au = {0.f,0.f,0.f,0.f}, ar = {0.f,0.f,0.f,0.f};
        #pragma unroll
        for (int ks = 0; ks < 8; ++ks) {
            const bf16x8 b = *(const bf16x8*)(&ldsF[swz8(nr, ks * 32 + q * 8)]);
            au = __builtin_amdgcn_mfma_f32_16x16x32_bf16(aU[ks], b, au, 0, 0, 0);
        }
        #pragma unroll
        for (int ks = 0; ks < 4; ++ks) {
            const bf16x8 b = *(const bf16x8*)(&ldsF[swz8(nr, ks * 32 + q * 8)]);
            ar = __builtin_amdgcn_mfma_f32_16x16x32_bf16(aR[ks], b, ar, 0, 0, 0);
        }
        __syncthreads();

        const int node = n0 + nr;
        float* dst = out + (long)node * C + chbase + q * 4;
        #pragma unroll
        for (int r = 0; r < 4; ++r)
            dst[r] = ar[r] + fmaxf(au[r] + bu[r], 0.f);
    }
}

extern "C" void kernel_launch(void* const* d_in, const int* in_sizes, int n_in,
                              void* d_out, int out_size, void* d_ws, size_t ws_size,
                              hipStream_t stream) {
    const float* embed = (const float*)d_in[0];
    const float* pos   = (const float*)d_in[1];
    const float* Wres  = (const float*)d_in[2];
    const float* Wmsg  = (const float*)d_in[3];
    const float* bmsg  = (const float*)d_in[4];
    const float* Wupd  = (const float*)d_in[5];
    const float* bupd  = (const float*)d_in[6];
    const int*   eidx  = (const int*)d_in[7];
    float* out = (float*)d_out;

    char* ws = (char*)d_ws;
    int*      bcnt = (int*)(ws + WS_BCNT);
    int*      boff = (int*)(ws + WS_BOFF);
    int*      gcur = (int*)(ws + WS_GCUR);
    int*      off  = (int*)(ws + WS_OFF);
    int*      srcS = (int*)(ws + WS_SRCS);
    unsigned* rec  = (unsigned*)(ws + WS_REC);
    __bf16*   HdstB= (__bf16*)(ws + WS_HDST);
    __bf16*   Hsrc = (__bf16*)(ws + WS_HSRC);

    precomp_kernel<<<1024, 512, 0, stream>>>(embed, Wmsg, bmsg, Hsrc, HdstB, bcnt);
    bcount_kernel<<<N_EDGES / 1024, 256, 0, stream>>>(eidx, bcnt);
    bscan_kernel<<<1, 256, 0, stream>>>(bcnt, boff, gcur, off);
    partition_kernel<<<N_EDGES / 1024, 256, 0, stream>>>(eidx, gcur, rec);
    bucket_csr_kernel<<<NB, 256, 0, stream>>>(rec, boff, off, srcS);
    aggr_kernel<<<4096, 256, 0, stream>>>(Hsrc, HdstB, pos, Wmsg, off, srcS, out);
    node_upd_kernel<<<1024, 512, 0, stream>>>(embed, Wres, Wupd, bupd, out);
}

// Round 7
// 120.441 us; speedup vs baseline: 1.1013x; 1.1013x over previous
//
#include <hip/hip_runtime.h>
#include <hip/hip_bf16.h>

#define N_NODES 50000
#define N_EDGES 640000
#define C 128            // IN_C == HID
#define NB 196           // dst buckets of 256 nodes (50000 <= 196*256)
#define NTILES (N_NODES / 16)                               // 3125

typedef __bf16 bf16x8 __attribute__((ext_vector_type(8)));
typedef __bf16 bf16x4 __attribute__((ext_vector_type(4)));
typedef float  f32x4  __attribute__((ext_vector_type(4)));
typedef unsigned int u32x4 __attribute__((ext_vector_type(4)));

// ---- d_ws layout (byte offsets) ----
#define WS_BCNT  0          // NB ints (bucket histogram; zeroed by precomp blk0)
#define WS_BOFF  1024       // NB+1 ints (bucket offsets)
#define WS_GCUR  2048       // NB ints (partition cursors)
#define WS_OFF   3072       // N+1 ints (CSR row offsets)
#define WS_SRCS  203776     // E ints (src ids grouped by dst)
#define WS_REC   2764800    // E u32 packed records
#define WS_HDST  5325312    // N*C bf16 (Hdst + bias)
#define WS_HSRC  18125824   // N*C bf16
// total ~30.9 MB

// XOR-swizzle for [16][128]-short LDS tiles (2-way residual conflict = free).
__device__ __forceinline__ int swzS(int row, int soff) {
    return row * 128 + (soff ^ ((row & 7) << 3));
}
// [16][256]-short variant (node-update staging)
__device__ __forceinline__ int swz8(int row, int soff) {
    return row * 256 + (soff ^ ((row & 7) << 3));
}

// ---------------------------------------------------------------------------
// Precompute Hsrc = embed @ Wmsg[0:128]          (bf16, ws)
//            Hdst = embed @ Wmsg[128:256] + b    (bf16, ws)
// Runs FIRST; block 0 also zeroes bcnt (replaces the tiny-fill dispatch).
// ---------------------------------------------------------------------------
__global__ __launch_bounds__(512) void precomp_kernel(
    const float* __restrict__ embed, const float* __restrict__ Wmsg,
    const float* __restrict__ bmsg,  __bf16* __restrict__ Hsrc,
    __bf16* __restrict__ Hdst, int* __restrict__ bcnt)
{
    __shared__ short lds[16 * 128];

    const int t = threadIdx.x, lane = t & 63, wave = t >> 6;
    const int chbase = wave * 16, q = lane >> 4, nr = lane & 15;
    const int ch = chbase + nr;

    if (blockIdx.x == 0 && t < NB) bcnt[t] = 0;

    bf16x8 aS[4], aD[4];
    #pragma unroll
    for (int ks = 0; ks < 4; ++ks)
        #pragma unroll
        for (int i = 0; i < 8; ++i) {
            const int k = ks * 32 + q * 8 + i;
            aS[ks][i] = (__bf16)Wmsg[k * C + ch];
            aD[ks][i] = (__bf16)Wmsg[(128 + k) * C + ch];
        }
    float bias[4];
    #pragma unroll
    for (int r = 0; r < 4; ++r) bias[r] = bmsg[chbase + q * 4 + r];

    for (int nt = blockIdx.x; nt < NTILES; nt += gridDim.x) {
        const int n0 = nt * 16;
        {   // stage 16 nodes x 128 feats: f32 -> bf16 LDS
            const int row = t >> 5, seg = t & 31;
            const float4 f = *(const float4*)(embed + (long)(n0 + row) * C + seg * 4);
            bf16x4 v;
            v[0]=(__bf16)f.x; v[1]=(__bf16)f.y; v[2]=(__bf16)f.z; v[3]=(__bf16)f.w;
            *(bf16x4*)(&lds[swzS(row, seg * 4)]) = v;
        }
        __syncthreads();

        f32x4 hs = {0.f,0.f,0.f,0.f}, hd = {0.f,0.f,0.f,0.f};
        #pragma unroll
        for (int ks = 0; ks < 4; ++ks) {
            const bf16x8 b = *(const bf16x8*)(&lds[swzS(nr, ks * 32 + q * 8)]);
            hs = __builtin_amdgcn_mfma_f32_16x16x32_bf16(aS[ks], b, hs, 0, 0, 0);
            hd = __builtin_amdgcn_mfma_f32_16x16x32_bf16(aD[ks], b, hd, 0, 0, 0);
        }
        __syncthreads();

        const int node = n0 + nr;            // D: col=node, row(q*4+r)=ch
        bf16x4 vs, vd;
        #pragma unroll
        for (int r = 0; r < 4; ++r) {
            vs[r] = (__bf16)hs[r];
            vd[r] = (__bf16)(hd[r] + bias[r]);
        }
        *(bf16x4*)(Hsrc + (long)node * C + chbase + q * 4) = vs;
        *(bf16x4*)(Hdst + (long)node * C + chbase + q * 4) = vd;
    }
}

// ---------------------------------------------------------------------------
// CSR build, bucket-sorted: bcount -> bscan -> partition -> bucket_csr
// ---------------------------------------------------------------------------
__global__ __launch_bounds__(256) void bcount_kernel(
    const int* __restrict__ eidx, int* __restrict__ bcnt)
{
    __shared__ int h[NB];
    const int t = threadIdx.x;
    if (t < NB) h[t] = 0;
    __syncthreads();
    const int e0 = blockIdx.x * 1024;
    #pragma unroll
    for (int k = 0; k < 4; ++k)
        atomicAdd(&h[eidx[N_EDGES + e0 + k * 256 + t] >> 8], 1);
    __syncthreads();
    if (t < NB) atomicAdd(&bcnt[t], h[t]);
}

__global__ __launch_bounds__(256) void bscan_kernel(
    const int* __restrict__ bcnt, int* __restrict__ boff,
    int* __restrict__ gcur, int* __restrict__ off)
{
    __shared__ int lds[256];
    const int t = threadIdx.x;
    const int v = (t < NB) ? bcnt[t] : 0;
    lds[t] = v;
    __syncthreads();
    for (int s = 1; s < 256; s <<= 1) {
        const int u = (t >= s) ? lds[t - s] : 0;
        __syncthreads();
        lds[t] += u;
        __syncthreads();
    }
    const int excl = lds[t] - v;
    if (t < NB) { boff[t] = excl; gcur[t] = excl; }
    if (t == 0) { boff[NB] = N_EDGES; off[N_NODES] = N_EDGES; }
}

__global__ __launch_bounds__(256) void partition_kernel(
    const int* __restrict__ eidx, int* __restrict__ gcur,
    unsigned* __restrict__ rec)
{
    __shared__ int cnt[NB];
    __shared__ int base[NB];
    const int t = threadIdx.x;
    if (t < NB) cnt[t] = 0;
    __syncthreads();
    const int e0 = blockIdx.x * 1024;
    int lrank[4], bb[4];
    unsigned prec[4];
    #pragma unroll
    for (int k = 0; k < 4; ++k) {
        const int e = e0 + k * 256 + t;
        const int r = eidx[e], c = eidx[N_EDGES + e];
        bb[k]   = c >> 8;
        prec[k] = (unsigned)r | ((unsigned)(c & 255) << 16);
        lrank[k] = atomicAdd(&cnt[bb[k]], 1);
    }
    __syncthreads();
    if (t < NB) base[t] = atomicAdd(&gcur[t], cnt[t]);
    __syncthreads();
    #pragma unroll
    for (int k = 0; k < 4; ++k)
        rec[base[bb[k]] + lrank[k]] = prec[k];
}

__global__ __launch_bounds__(256) void bucket_csr_kernel(
    const unsigned* __restrict__ rec, const int* __restrict__ boff,
    int* __restrict__ off, int* __restrict__ srcS)
{
    __shared__ int deg[256];
    __shared__ int cur[256];
    __shared__ int lds[256];
    const int t = threadIdx.x, b = blockIdx.x;
    const int r0 = boff[b], r1 = boff[b + 1], n0 = b << 8;
    deg[t] = 0;
    __syncthreads();
    for (int i = r0 + t; i < r1; i += 256)
        atomicAdd(&deg[rec[i] >> 16], 1);
    __syncthreads();
    const int v = deg[t];
    lds[t] = v;
    __syncthreads();
    for (int s = 1; s < 256; s <<= 1) {
        const int u = (t >= s) ? lds[t - s] : 0;
        __syncthreads();
        lds[t] += u;
        __syncthreads();
    }
    const int excl = r0 + lds[t] - v;
    cur[t] = excl;
    if (n0 + t < N_NODES) off[n0 + t] = excl;
    __syncthreads();
    for (int i = r0 + t; i < r1; i += 256) {
        const unsigned rc = rec[i];
        const int p = atomicAdd(&cur[rc >> 16], 1);
        srcS[p] = (int)(rc & 0xFFFFu);
    }
}

// ---------------------------------------------------------------------------
// Aggregate: one node per wave, 4 groups x 16 lanes (8 ch/lane), DEPTH-2
// pipeline: 8 edges per iteration, both halves' gathers issued before use,
// next ids prefetched. No LDS, no barriers, no atomics; writes out once.
// ---------------------------------------------------------------------------
__global__ __launch_bounds__(256) void aggr_kernel(
    const __bf16* __restrict__ Hsrc, const __bf16* __restrict__ Hdst,
    const float*  __restrict__ pos,  const float* __restrict__ Wmsg,
    const int*    __restrict__ off,  const int*   __restrict__ srcS,
    float* __restrict__ out)
{
    const int lane = threadIdx.x & 63;
    const int wv   = threadIdx.x >> 6;
    const int g    = lane >> 4;          // edge sub-group 0..3
    const int c8   = (lane & 15) * 8;    // channel base (8 ch/lane)

    float w2[8], hd[8], acc[8];
    *(f32x4*)&w2[0] = *(const f32x4*)(Wmsg + 256 * C + c8);
    *(f32x4*)&w2[4] = *(const f32x4*)(Wmsg + 256 * C + c8 + 4);

    const int gw = blockIdx.x * 4 + wv;
    const int nw = gridDim.x * 4;
    for (int n = gw; n < N_NODES; n += nw) {
        const int o0 = off[n], o1 = off[n + 1];
        {   // unpack Hdst row slice (bf16 -> f32)
            const u32x4 hdb = *(const u32x4*)(Hdst + (long)n * C + c8);
            #pragma unroll
            for (int k = 0; k < 4; ++k) {
                hd[2*k]   = __uint_as_float(hdb[k] << 16);
                hd[2*k+1] = __uint_as_float(hdb[k] & 0xffff0000u);
            }
        }
        const float px = pos[n * 3], py = pos[n * 3 + 1], pz = pos[n * 3 + 2];
        #pragma unroll
        for (int j = 0; j < 8; ++j) acc[j] = 0.f;

        if (o1 > o0) {
            const int last = o1 - 1;
            int s0 = srcS[min(o0 + g,     last)];
            int s1 = srcS[min(o0 + 4 + g, last)];
            for (int e = o0; e < o1; e += 8) {
                // issue both halves' gathers, then prefetch next ids
                const float qx0 = pos[s0*3], qy0 = pos[s0*3+1], qz0 = pos[s0*3+2];
                const u32x4 hu0 = *(const u32x4*)(Hsrc + (long)s0 * C + c8);
                const float qx1 = pos[s1*3], qy1 = pos[s1*3+1], qz1 = pos[s1*3+2];
                const u32x4 hu1 = *(const u32x4*)(Hsrc + (long)s1 * C + c8);
                const int sn0 = srcS[min(e + 8  + g, last)];
                const int sn1 = srcS[min(e + 12 + g, last)];

                {   // half 0: edge e+g
                    const float dx = qx0 - px, dy = qy0 - py, dz = qz0 - pz;
                    const float d  = dx * dx + dy * dy + dz * dz;
                    const bool valid = (e + g) < o1;
                    #pragma unroll
                    for (int k = 0; k < 4; ++k) {
                        const float flo = __uint_as_float(hu0[k] << 16);
                        const float fhi = __uint_as_float(hu0[k] & 0xffff0000u);
                        const float v0 = fmaxf(flo + hd[2*k]   + d * w2[2*k],   0.f);
                        const float v1 = fmaxf(fhi + hd[2*k+1] + d * w2[2*k+1], 0.f);
                        acc[2*k]   += valid ? v0 : 0.f;
                        acc[2*k+1] += valid ? v1 : 0.f;
                    }
                }
                {   // half 1: edge e+4+g
                    const float dx = qx1 - px, dy = qy1 - py, dz = qz1 - pz;
                    const float d  = dx * dx + dy * dy + dz * dz;
                    const bool valid = (e + 4 + g) < o1;
                    #pragma unroll
                    for (int k = 0; k < 4; ++k) {
                        const float flo = __uint_as_float(hu1[k] << 16);
                        const float fhi = __uint_as_float(hu1[k] & 0xffff0000u);
                        const float v0 = fmaxf(flo + hd[2*k]   + d * w2[2*k],   0.f);
                        const float v1 = fmaxf(fhi + hd[2*k+1] + d * w2[2*k+1], 0.f);
                        acc[2*k]   += valid ? v0 : 0.f;
                        acc[2*k+1] += valid ? v1 : 0.f;
                    }
                }
                s0 = sn0; s1 = sn1;
            }
        }
        #pragma unroll
        for (int j = 0; j < 8; ++j) {        // combine the 4 edge groups
            acc[j] += __shfl_xor(acc[j], 16);
            acc[j] += __shfl_xor(acc[j], 32);
        }
        if (lane < 16) {
            *(f32x4*)(out + (long)n * C + c8)     = *(const f32x4*)&acc[0];
            *(f32x4*)(out + (long)n * C + c8 + 4) = *(const f32x4*)&acc[4];
        }
    }
}

// ---------------------------------------------------------------------------
// Node update: out = embed @ W_res + relu([embed, aggr] @ W_upd + b_upd)
// (aggr lives in `out` on entry; overwritten in place, single-owner tiles)
// ---------------------------------------------------------------------------
__global__ __launch_bounds__(512) void node_upd_kernel(
    const float* __restrict__ embed, const float* __restrict__ Wres,
    const float* __restrict__ Wupd,  const float* __restrict__ bupd,
    float* __restrict__ out)
{
    __shared__ short ldsF[16 * 256];

    const int t = threadIdx.x, lane = t & 63, wave = t >> 6;
    const int chbase = wave * 16, q = lane >> 4, nr = lane & 15;

    bf16x8 aU[8], aR[4];
    {
        const int ch = chbase + nr;
        #pragma unroll
        for (int ks = 0; ks < 8; ++ks)
            #pragma unroll
            for (int i = 0; i < 8; ++i)
                aU[ks][i] = (__bf16)Wupd[(ks*32 + q*8 + i) * C + ch];
        #pragma unroll
        for (int ks = 0; ks < 4; ++ks)
            #pragma unroll
            for (int i = 0; i < 8; ++i)
                aR[ks][i] = (__bf16)Wres[(ks*32 + q*8 + i) * C + ch];
    }
    float bu[4];
    #pragma unroll
    for (int r = 0; r < 4; ++r) bu[r] = bupd[chbase + q*4 + r];

    for (int nt = blockIdx.x; nt < NTILES; nt += gridDim.x) {
        const int n0 = nt * 16;
        {   // stage [embed(f32->bf16) | aggr(f32 in out)] for 16 nodes
            const int nn = t >> 5, seg = t & 31;
            const float* base = (seg < 16) ? embed : out;
            const float* src  = base + (long)(n0 + nn) * C + (seg & 15) * 8;
            const float4 f0 = *(const float4*)src;
            const float4 f1 = *(const float4*)(src + 4);
            bf16x8 v;
            v[0]=(__bf16)f0.x; v[1]=(__bf16)f0.y; v[2]=(__bf16)f0.z; v[3]=(__bf16)f0.w;
            v[4]=(__bf16)f1.x; v[5]=(__bf16)f1.y; v[6]=(__bf16)f1.z; v[7]=(__bf16)f1.w;
            *(bf16x8*)(&ldsF[swz8(nn, seg * 8)]) = v;
        }
        __syncthreads();

        f32x4 au = {0.f,0.f,0.f,0.f}, ar = {0.f,0.f,0.f,0.f};
        #pragma unroll
        for (int ks = 0; ks < 8; ++ks) {
            const bf16x8 b = *(const bf16x8*)(&ldsF[swz8(nr, ks * 32 + q * 8)]);
            au = __builtin_amdgcn_mfma_f32_16x16x32_bf16(aU[ks], b, au, 0, 0, 0);
        }
        #pragma unroll
        for (int ks = 0; ks < 4; ++ks) {
            const bf16x8 b = *(const bf16x8*)(&ldsF[swz8(nr, ks * 32 + q * 8)]);
            ar = __builtin_amdgcn_mfma_f32_16x16x32_bf16(aR[ks], b, ar, 0, 0, 0);
        }
        __syncthreads();

        const int node = n0 + nr;
        float* dst = out + (long)node * C + chbase + q * 4;
        #pragma unroll
        for (int r = 0; r < 4; ++r)
            dst[r] = ar[r] + fmaxf(au[r] + bu[r], 0.f);
    }
}

extern "C" void kernel_launch(void* const* d_in, const int* in_sizes, int n_in,
                              void* d_out, int out_size, void* d_ws, size_t ws_size,
                              hipStream_t stream) {
    const float* embed = (const float*)d_in[0];
    const float* pos   = (const float*)d_in[1];
    const float* Wres  = (const float*)d_in[2];
    const float* Wmsg  = (const float*)d_in[3];
    const float* bmsg  = (const float*)d_in[4];
    const float* Wupd  = (const float*)d_in[5];
    const float* bupd  = (const float*)d_in[6];
    const int*   eidx  = (const int*)d_in[7];
    float* out = (float*)d_out;

    char* ws = (char*)d_ws;
    int*      bcnt = (int*)(ws + WS_BCNT);
    int*      boff = (int*)(ws + WS_BOFF);
    int*      gcur = (int*)(ws + WS_GCUR);
    int*      off  = (int*)(ws + WS_OFF);
    int*      srcS = (int*)(ws + WS_SRCS);
    unsigned* rec  = (unsigned*)(ws + WS_REC);
    __bf16*   HdstB= (__bf16*)(ws + WS_HDST);
    __bf16*   Hsrc = (__bf16*)(ws + WS_HSRC);

    precomp_kernel<<<1024, 512, 0, stream>>>(embed, Wmsg, bmsg, Hsrc, HdstB, bcnt);
    bcount_kernel<<<N_EDGES / 1024, 256, 0, stream>>>(eidx, bcnt);
    bscan_kernel<<<1, 256, 0, stream>>>(bcnt, boff, gcur, off);
    partition_kernel<<<N_EDGES / 1024, 256, 0, stream>>>(eidx, gcur, rec);
    bucket_csr_kernel<<<NB, 256, 0, stream>>>(rec, boff, off, srcS);
    aggr_kernel<<<6144, 256, 0, stream>>>(Hsrc, HdstB, pos, Wmsg, off, srcS, out);
    node_upd_kernel<<<1024, 512, 0, stream>>>(embed, Wres, Wupd, bupd, out);
}

// Round 8
// 118.225 us; speedup vs baseline: 1.1220x; 1.0187x over previous
//
#include <hip/hip_runtime.h>
#include <hip/hip_bf16.h>

#define N_NODES 50000
#define N_EDGES 640000
#define C 128            // IN_C == HID
#define NB 196           // dst buckets of 256 nodes (50000 <= 196*256)
#define NTILES (N_NODES / 16)                               // 3125

typedef __bf16 bf16x8 __attribute__((ext_vector_type(8)));
typedef __bf16 bf16x4 __attribute__((ext_vector_type(4)));
typedef float  f32x4  __attribute__((ext_vector_type(4)));
typedef unsigned int u32x4 __attribute__((ext_vector_type(4)));

// ---- d_ws layout (byte offsets) ----
#define WS_BCNT  0          // NB ints (bucket histogram; zeroed by precomp blk0)
#define WS_GCUR  1024       // NB ints (partition cursors, zero-based)
#define WS_OFF   3072       // N+1 ints (CSR row offsets)
#define WS_SRCS  203776     // E ints (src ids grouped by dst)
#define WS_REC   2764800    // E u32 packed records
#define WS_HDST  5325312    // N*C bf16 (Hdst + bias)
#define WS_HSRC  18125824   // N*C bf16
// total ~30.9 MB

// XOR-swizzle for [16][128]-short LDS tiles (2-way residual conflict = free).
__device__ __forceinline__ int swzS(int row, int soff) {
    return row * 128 + (soff ^ ((row & 7) << 3));
}
// [16][256]-short variant (node-update staging)
__device__ __forceinline__ int swz8(int row, int soff) {
    return row * 256 + (soff ^ ((row & 7) << 3));
}

// ---------------------------------------------------------------------------
// Precompute Hsrc = embed @ Wmsg[0:128]          (bf16, ws)
//            Hdst = embed @ Wmsg[128:256] + b    (bf16, ws)
// Runs FIRST; block 0 also zeroes bcnt+gcur (replaces tiny-fill dispatches).
// ---------------------------------------------------------------------------
__global__ __launch_bounds__(512) void precomp_kernel(
    const float* __restrict__ embed, const float* __restrict__ Wmsg,
    const float* __restrict__ bmsg,  __bf16* __restrict__ Hsrc,
    __bf16* __restrict__ Hdst, int* __restrict__ bcnt, int* __restrict__ gcur)
{
    __shared__ short lds[16 * 128];

    const int t = threadIdx.x, lane = t & 63, wave = t >> 6;
    const int chbase = wave * 16, q = lane >> 4, nr = lane & 15;
    const int ch = chbase + nr;

    if (blockIdx.x == 0 && t < NB) { bcnt[t] = 0; gcur[t] = 0; }

    bf16x8 aS[4], aD[4];
    #pragma unroll
    for (int ks = 0; ks < 4; ++ks)
        #pragma unroll
        for (int i = 0; i < 8; ++i) {
            const int k = ks * 32 + q * 8 + i;
            aS[ks][i] = (__bf16)Wmsg[k * C + ch];
            aD[ks][i] = (__bf16)Wmsg[(128 + k) * C + ch];
        }
    float bias[4];
    #pragma unroll
    for (int r = 0; r < 4; ++r) bias[r] = bmsg[chbase + q * 4 + r];

    for (int nt = blockIdx.x; nt < NTILES; nt += gridDim.x) {
        const int n0 = nt * 16;
        {   // stage 16 nodes x 128 feats: f32 -> bf16 LDS
            const int row = t >> 5, seg = t & 31;
            const float4 f = *(const float4*)(embed + (long)(n0 + row) * C + seg * 4);
            bf16x4 v;
            v[0]=(__bf16)f.x; v[1]=(__bf16)f.y; v[2]=(__bf16)f.z; v[3]=(__bf16)f.w;
            *(bf16x4*)(&lds[swzS(row, seg * 4)]) = v;
        }
        __syncthreads();

        f32x4 hs = {0.f,0.f,0.f,0.f}, hd = {0.f,0.f,0.f,0.f};
        #pragma unroll
        for (int ks = 0; ks < 4; ++ks) {
            const bf16x8 b = *(const bf16x8*)(&lds[swzS(nr, ks * 32 + q * 8)]);
            hs = __builtin_amdgcn_mfma_f32_16x16x32_bf16(aS[ks], b, hs, 0, 0, 0);
            hd = __builtin_amdgcn_mfma_f32_16x16x32_bf16(aD[ks], b, hd, 0, 0, 0);
        }
        __syncthreads();

        const int node = n0 + nr;            // D: col=node, row(q*4+r)=ch
        bf16x4 vs, vd;
        #pragma unroll
        for (int r = 0; r < 4; ++r) {
            vs[r] = (__bf16)hs[r];
            vd[r] = (__bf16)(hd[r] + bias[r]);
        }
        *(bf16x4*)(Hsrc + (long)node * C + chbase + q * 4) = vs;
        *(bf16x4*)(Hdst + (long)node * C + chbase + q * 4) = vd;
    }
}

// ---------------------------------------------------------------------------
// CSR build, bucket-sorted: bcount -> partition -> bucket_csr
// (bucket prefix recomputed in-block; no bscan dispatch)
// ---------------------------------------------------------------------------
__global__ __launch_bounds__(256) void bcount_kernel(
    const int* __restrict__ eidx, int* __restrict__ bcnt)
{
    __shared__ int h[NB];
    const int t = threadIdx.x;
    if (t < NB) h[t] = 0;
    __syncthreads();
    const int e0 = blockIdx.x * 1024;
    #pragma unroll
    for (int k = 0; k < 4; ++k)
        atomicAdd(&h[eidx[N_EDGES + e0 + k * 256 + t] >> 8], 1);
    __syncthreads();
    if (t < NB) atomicAdd(&bcnt[t], h[t]);
}

// bin 1024 edges/block by dst>>8 via LDS cursors; in-block 196-int scan gives
// bucket bases; reserve ranges with one global atomic per bucket per block;
// write packed 4B records (src | dstLocal<<16) in within-bucket runs.
__global__ __launch_bounds__(256) void partition_kernel(
    const int* __restrict__ eidx, const int* __restrict__ bcnt,
    int* __restrict__ gcur, unsigned* __restrict__ rec)
{
    __shared__ int cnt[NB];
    __shared__ int base[NB];
    __shared__ int scan[256];
    const int t = threadIdx.x;
    const int bv = (t < NB) ? bcnt[t] : 0;
    scan[t] = bv;
    if (t < NB) cnt[t] = 0;
    __syncthreads();
    for (int s = 1; s < 256; s <<= 1) {
        const int u = (t >= s) ? scan[t - s] : 0;
        __syncthreads();
        scan[t] += u;
        __syncthreads();
    }
    const int e0 = blockIdx.x * 1024;
    int lrank[4], bb[4];
    unsigned prec[4];
    #pragma unroll
    for (int k = 0; k < 4; ++k) {
        const int e = e0 + k * 256 + t;
        const int r = eidx[e], c = eidx[N_EDGES + e];
        bb[k]   = c >> 8;
        prec[k] = (unsigned)r | ((unsigned)(c & 255) << 16);
        lrank[k] = atomicAdd(&cnt[bb[k]], 1);
    }
    __syncthreads();
    if (t < NB) base[t] = (scan[t] - bv) + atomicAdd(&gcur[t], cnt[t]);
    __syncthreads();
    #pragma unroll
    for (int k = 0; k < 4; ++k)
        rec[base[bb[k]] + lrank[k]] = prec[k];
}

// one block per bucket: in-block bucket prefix -> [r0,r1); LDS deg-count over
// 256 nodes -> scan -> off[]; LDS-cursor scatter into contiguous srcS range.
__global__ __launch_bounds__(256) void bucket_csr_kernel(
    const unsigned* __restrict__ rec, const int* __restrict__ bcnt,
    int* __restrict__ off, int* __restrict__ srcS)
{
    __shared__ int deg[256];
    __shared__ int cur[256];
    __shared__ int lds[256];
    const int t = threadIdx.x, b = blockIdx.x;
    const int bv = (t < NB) ? bcnt[t] : 0;
    lds[t] = bv;
    deg[t] = 0;
    __syncthreads();
    for (int s = 1; s < 256; s <<= 1) {
        const int u = (t >= s) ? lds[t - s] : 0;
        __syncthreads();
        lds[t] += u;
        __syncthreads();
    }
    const int r1 = lds[b];                 // inclusive prefix at bucket b
    const int r0 = r1 - bcnt[b];
    const int n0 = b << 8;
    __syncthreads();                       // lds reused below

    for (int i = r0 + t; i < r1; i += 256)
        atomicAdd(&deg[rec[i] >> 16], 1);
    __syncthreads();
    const int v = deg[t];
    lds[t] = v;
    __syncthreads();
    for (int s = 1; s < 256; s <<= 1) {
        const int u = (t >= s) ? lds[t - s] : 0;
        __syncthreads();
        lds[t] += u;
        __syncthreads();
    }
    const int excl = r0 + lds[t] - v;
    cur[t] = excl;
    if (n0 + t < N_NODES) off[n0 + t] = excl;
    if (b == NB - 1 && t == 0) off[N_NODES] = N_EDGES;
    __syncthreads();
    for (int i = r0 + t; i < r1; i += 256) {
        const unsigned rc = rec[i];
        const int p = atomicAdd(&cur[rc >> 16], 1);
        srcS[p] = (int)(rc & 0xFFFFu);
    }
}

// ---------------------------------------------------------------------------
// Aggregate: ONE NODE PER WAVE (grid*4 == N_NODES), 4 groups x 16 lanes
// (8 ch/lane), depth-2 pipeline (8 edges/iter in flight). No LDS/barriers/
// atomics; writes out exactly once.
// ---------------------------------------------------------------------------
__global__ __launch_bounds__(256) void aggr_kernel(
    const __bf16* __restrict__ Hsrc, const __bf16* __restrict__ Hdst,
    const float*  __restrict__ pos,  const float* __restrict__ Wmsg,
    const int*    __restrict__ off,  const int*   __restrict__ srcS,
    float* __restrict__ out)
{
    const int lane = threadIdx.x & 63;
    const int wv   = threadIdx.x >> 6;
    const int g    = lane >> 4;          // edge sub-group 0..3
    const int c8   = (lane & 15) * 8;    // channel base (8 ch/lane)

    float w2[8], hd[8], acc[8];
    *(f32x4*)&w2[0] = *(const f32x4*)(Wmsg + 256 * C + c8);
    *(f32x4*)&w2[4] = *(const f32x4*)(Wmsg + 256 * C + c8 + 4);

    const int n = blockIdx.x * 4 + wv;   // 12500*4 == 50000 exactly
    const int o0 = off[n], o1 = off[n + 1];
    {   // unpack Hdst row slice (bf16 -> f32)
        const u32x4 hdb = *(const u32x4*)(Hdst + (long)n * C + c8);
        #pragma unroll
        for (int k = 0; k < 4; ++k) {
            hd[2*k]   = __uint_as_float(hdb[k] << 16);
            hd[2*k+1] = __uint_as_float(hdb[k] & 0xffff0000u);
        }
    }
    const float px = pos[n * 3], py = pos[n * 3 + 1], pz = pos[n * 3 + 2];
    #pragma unroll
    for (int j = 0; j < 8; ++j) acc[j] = 0.f;

    if (o1 > o0) {
        const int last = o1 - 1;
        int s0 = srcS[min(o0 + g,     last)];
        int s1 = srcS[min(o0 + 4 + g, last)];
        for (int e = o0; e < o1; e += 8) {
            // issue both halves' gathers, then prefetch next ids
            const float qx0 = pos[s0*3], qy0 = pos[s0*3+1], qz0 = pos[s0*3+2];
            const u32x4 hu0 = *(const u32x4*)(Hsrc + (long)s0 * C + c8);
            const float qx1 = pos[s1*3], qy1 = pos[s1*3+1], qz1 = pos[s1*3+2];
            const u32x4 hu1 = *(const u32x4*)(Hsrc + (long)s1 * C + c8);
            const int sn0 = srcS[min(e + 8  + g, last)];
            const int sn1 = srcS[min(e + 12 + g, last)];

            {   // half 0: edge e+g
                const float dx = qx0 - px, dy = qy0 - py, dz = qz0 - pz;
                const float d  = dx * dx + dy * dy + dz * dz;
                const bool valid = (e + g) < o1;
                #pragma unroll
                for (int k = 0; k < 4; ++k) {
                    const float flo = __uint_as_float(hu0[k] << 16);
                    const float fhi = __uint_as_float(hu0[k] & 0xffff0000u);
                    const float v0 = fmaxf(flo + hd[2*k]   + d * w2[2*k],   0.f);
                    const float v1 = fmaxf(fhi + hd[2*k+1] + d * w2[2*k+1], 0.f);
                    acc[2*k]   += valid ? v0 : 0.f;
                    acc[2*k+1] += valid ? v1 : 0.f;
                }
            }
            {   // half 1: edge e+4+g
                const float dx = qx1 - px, dy = qy1 - py, dz = qz1 - pz;
                const float d  = dx * dx + dy * dy + dz * dz;
                const bool valid = (e + 4 + g) < o1;
                #pragma unroll
                for (int k = 0; k < 4; ++k) {
                    const float flo = __uint_as_float(hu1[k] << 16);
                    const float fhi = __uint_as_float(hu1[k] & 0xffff0000u);
                    const float v0 = fmaxf(flo + hd[2*k]   + d * w2[2*k],   0.f);
                    const float v1 = fmaxf(fhi + hd[2*k+1] + d * w2[2*k+1], 0.f);
                    acc[2*k]   += valid ? v0 : 0.f;
                    acc[2*k+1] += valid ? v1 : 0.f;
                }
            }
            s0 = sn0; s1 = sn1;
        }
    }
    #pragma unroll
    for (int j = 0; j < 8; ++j) {        // combine the 4 edge groups
        acc[j] += __shfl_xor(acc[j], 16);
        acc[j] += __shfl_xor(acc[j], 32);
    }
    if (lane < 16) {
        *(f32x4*)(out + (long)n * C + c8)     = *(const f32x4*)&acc[0];
        *(f32x4*)(out + (long)n * C + c8 + 4) = *(const f32x4*)&acc[4];
    }
}

// ---------------------------------------------------------------------------
// Node update: out = embed @ W_res + relu([embed, aggr] @ W_upd + b_upd)
// (aggr lives in `out` on entry; overwritten in place, single-owner tiles)
// ---------------------------------------------------------------------------
__global__ __launch_bounds__(512) void node_upd_kernel(
    const float* __restrict__ embed, const float* __restrict__ Wres,
    const float* __restrict__ Wupd,  const float* __restrict__ bupd,
    float* __restrict__ out)
{
    __shared__ short ldsF[16 * 256];

    const int t = threadIdx.x, lane = t & 63, wave = t >> 6;
    const int chbase = wave * 16, q = lane >> 4, nr = lane & 15;

    bf16x8 aU[8], aR[4];
    {
        const int ch = chbase + nr;
        #pragma unroll
        for (int ks = 0; ks < 8; ++ks)
            #pragma unroll
            for (int i = 0; i < 8; ++i)
                aU[ks][i] = (__bf16)Wupd[(ks*32 + q*8 + i) * C + ch];
        #pragma unroll
        for (int ks = 0; ks < 4; ++ks)
            #pragma unroll
            for (int i = 0; i < 8; ++i)
                aR[ks][i] = (__bf16)Wres[(ks*32 + q*8 + i) * C + ch];
    }
    float bu[4];
    #pragma unroll
    for (int r = 0; r < 4; ++r) bu[r] = bupd[chbase + q*4 + r];

    for (int nt = blockIdx.x; nt < NTILES; nt += gridDim.x) {
        const int n0 = nt * 16;
        {   // stage [embed(f32->bf16) | aggr(f32 in out)] for 16 nodes
            const int nn = t >> 5, seg = t & 31;
            const float* base = (seg < 16) ? embed : out;
            const float* src  = base + (long)(n0 + nn) * C + (seg & 15) * 8;
            const float4 f0 = *(const float4*)src;
            const float4 f1 = *(const float4*)(src + 4);
            bf16x8 v;
            v[0]=(__bf16)f0.x; v[1]=(__bf16)f0.y; v[2]=(__bf16)f0.z; v[3]=(__bf16)f0.w;
            v[4]=(__bf16)f1.x; v[5]=(__bf16)f1.y; v[6]=(__bf16)f1.z; v[7]=(__bf16)f1.w;
            *(bf16x8*)(&ldsF[swz8(nn, seg * 8)]) = v;
        }
        __syncthreads();

        f32x4 au = {0.f,0.f,0.f,0.f}, ar = {0.f,0.f,0.f,0.f};
        #pragma unroll
        for (int ks = 0; ks < 8; ++ks) {
            const bf16x8 b = *(const bf16x8*)(&ldsF[swz8(nr, ks * 32 + q * 8)]);
            au = __builtin_amdgcn_mfma_f32_16x16x32_bf16(aU[ks], b, au, 0, 0, 0);
        }
        #pragma unroll
        for (int ks = 0; ks < 4; ++ks) {
            const bf16x8 b = *(const bf16x8*)(&ldsF[swz8(nr, ks * 32 + q * 8)]);
            ar = __builtin_amdgcn_mfma_f32_16x16x32_bf16(aR[ks], b, ar, 0, 0, 0);
        }
        __syncthreads();

        const int node = n0 + nr;
        float* dst = out + (long)node * C + chbase + q * 4;
        #pragma unroll
        for (int r = 0; r < 4; ++r)
            dst[r] = ar[r] + fmaxf(au[r] + bu[r], 0.f);
    }
}

extern "C" void kernel_launch(void* const* d_in, const int* in_sizes, int n_in,
                              void* d_out, int out_size, void* d_ws, size_t ws_size,
                              hipStream_t stream) {
    const float* embed = (const float*)d_in[0];
    const float* pos   = (const float*)d_in[1];
    const float* Wres  = (const float*)d_in[2];
    const float* Wmsg  = (const float*)d_in[3];
    const float* bmsg  = (const float*)d_in[4];
    const float* Wupd  = (const float*)d_in[5];
    const float* bupd  = (const float*)d_in[6];
    const int*   eidx  = (const int*)d_in[7];
    float* out = (float*)d_out;

    char* ws = (char*)d_ws;
    int*      bcnt = (int*)(ws + WS_BCNT);
    int*      gcur = (int*)(ws + WS_GCUR);
    int*      off  = (int*)(ws + WS_OFF);
    int*      srcS = (int*)(ws + WS_SRCS);
    unsigned* rec  = (unsigned*)(ws + WS_REC);
    __bf16*   HdstB= (__bf16*)(ws + WS_HDST);
    __bf16*   Hsrc = (__bf16*)(ws + WS_HSRC);

    precomp_kernel<<<1024, 512, 0, stream>>>(embed, Wmsg, bmsg, Hsrc, HdstB, bcnt, gcur);
    bcount_kernel<<<N_EDGES / 1024, 256, 0, stream>>>(eidx, bcnt);
    partition_kernel<<<N_EDGES / 1024, 256, 0, stream>>>(eidx, bcnt, gcur, rec);
    bucket_csr_kernel<<<NB, 256, 0, stream>>>(rec, bcnt, off, srcS);
    aggr_kernel<<<N_NODES / 4, 256, 0, stream>>>(Hsrc, HdstB, pos, Wmsg, off, srcS, out);
    node_upd_kernel<<<1024, 512, 0, stream>>>(embed, Wres, Wupd, bupd, out);
}

// Round 9
// 105.240 us; speedup vs baseline: 1.2604x; 1.1234x over previous
//
#include <hip/hip_runtime.h>
#include <hip/hip_bf16.h>

#define N_NODES 50000
#define N_EDGES 640000
#define C 128            // IN_C == HID
#define NB 196           // dst buckets of 256 nodes (50000 <= 196*256)
#define BCAP 4096        // fixed edge capacity per bucket (mean 3277, +14 sigma)
#define NTILES (N_NODES / 16)                               // 3125

typedef __bf16 bf16x8 __attribute__((ext_vector_type(8)));
typedef __bf16 bf16x4 __attribute__((ext_vector_type(4)));
typedef float  f32x4  __attribute__((ext_vector_type(4)));
typedef unsigned int u32x4 __attribute__((ext_vector_type(4)));

// ---- d_ws layout (byte offsets) ----
#define WS_GCUR  0          // NB ints (bucket cursors; zeroed by precomp blk0)
#define WS_OFFS  1024       // N ints (per-node edge range start)
#define WS_OFFE  201024     // N ints (per-node edge range end)
#define WS_SRCS  401024     // NB*BCAP ints (src ids, bucketed)
#define WS_REC   3612288    // NB*BCAP u32 packed records
#define WS_HDST  6823552    // N*C bf16 (Hdst + bias)
#define WS_HSRC  19623552   // N*C bf16
#define WS_AGGR  32423552   // N*C bf16 (aggregation result)
// total ~45.2 MB

// XOR-swizzle for [16][128]-short LDS tiles (2-way residual conflict = free).
__device__ __forceinline__ int swzS(int row, int soff) {
    return row * 128 + (soff ^ ((row & 7) << 3));
}
// [16][256]-short variant (node-update staging)
__device__ __forceinline__ int swz8(int row, int soff) {
    return row * 256 + (soff ^ ((row & 7) << 3));
}

// ---------------------------------------------------------------------------
// Precompute Hsrc = embed @ Wmsg[0:128]          (bf16, ws)
//            Hdst = embed @ Wmsg[128:256] + b    (bf16, ws)
// Runs FIRST; block 0 also zeroes gcur (stream order covers the dependency).
// ---------------------------------------------------------------------------
__global__ __launch_bounds__(512) void precomp_kernel(
    const float* __restrict__ embed, const float* __restrict__ Wmsg,
    const float* __restrict__ bmsg,  __bf16* __restrict__ Hsrc,
    __bf16* __restrict__ Hdst, int* __restrict__ gcur)
{
    __shared__ short lds[16 * 128];

    const int t = threadIdx.x, lane = t & 63, wave = t >> 6;
    const int chbase = wave * 16, q = lane >> 4, nr = lane & 15;
    const int ch = chbase + nr;

    if (blockIdx.x == 0 && t < NB) gcur[t] = 0;

    bf16x8 aS[4], aD[4];
    #pragma unroll
    for (int ks = 0; ks < 4; ++ks)
        #pragma unroll
        for (int i = 0; i < 8; ++i) {
            const int k = ks * 32 + q * 8 + i;
            aS[ks][i] = (__bf16)Wmsg[k * C + ch];
            aD[ks][i] = (__bf16)Wmsg[(128 + k) * C + ch];
        }
    float bias[4];
    #pragma unroll
    for (int r = 0; r < 4; ++r) bias[r] = bmsg[chbase + q * 4 + r];

    for (int nt = blockIdx.x; nt < NTILES; nt += gridDim.x) {
        const int n0 = nt * 16;
        {   // stage 16 nodes x 128 feats: f32 -> bf16 LDS
            const int row = t >> 5, seg = t & 31;
            const float4 f = *(const float4*)(embed + (long)(n0 + row) * C + seg * 4);
            bf16x4 v;
            v[0]=(__bf16)f.x; v[1]=(__bf16)f.y; v[2]=(__bf16)f.z; v[3]=(__bf16)f.w;
            *(bf16x4*)(&lds[swzS(row, seg * 4)]) = v;
        }
        __syncthreads();

        f32x4 hs = {0.f,0.f,0.f,0.f}, hd = {0.f,0.f,0.f,0.f};
        #pragma unroll
        for (int ks = 0; ks < 4; ++ks) {
            const bf16x8 b = *(const bf16x8*)(&lds[swzS(nr, ks * 32 + q * 8)]);
            hs = __builtin_amdgcn_mfma_f32_16x16x32_bf16(aS[ks], b, hs, 0, 0, 0);
            hd = __builtin_amdgcn_mfma_f32_16x16x32_bf16(aD[ks], b, hd, 0, 0, 0);
        }
        __syncthreads();

        const int node = n0 + nr;            // D: col=node, row(q*4+r)=ch
        bf16x4 vs, vd;
        #pragma unroll
        for (int r = 0; r < 4; ++r) {
            vs[r] = (__bf16)hs[r];
            vd[r] = (__bf16)(hd[r] + bias[r]);
        }
        *(bf16x4*)(Hsrc + (long)node * C + chbase + q * 4) = vs;
        *(bf16x4*)(Hdst + (long)node * C + chbase + q * 4) = vd;
    }
}

// ---------------------------------------------------------------------------
// partition: bin 1024 edges/block by dst>>8 via LDS counters; reserve a range
// in the bucket's FIXED slot [b*BCAP, (b+1)*BCAP) with one global atomic per
// bucket per block; write packed 4B records (src | dstLocal<<16).
// ---------------------------------------------------------------------------
__global__ __launch_bounds__(256) void partition_kernel(
    const int* __restrict__ eidx, int* __restrict__ gcur,
    unsigned* __restrict__ rec)
{
    __shared__ int cnt[NB];
    __shared__ int base[NB];
    const int t = threadIdx.x;
    if (t < NB) cnt[t] = 0;
    __syncthreads();
    const int e0 = blockIdx.x * 1024;
    int lrank[4], bb[4];
    unsigned prec[4];
    #pragma unroll
    for (int k = 0; k < 4; ++k) {
        const int e = e0 + k * 256 + t;
        const int r = eidx[e], c = eidx[N_EDGES + e];
        bb[k]   = c >> 8;
        prec[k] = (unsigned)r | ((unsigned)(c & 255) << 16);
        lrank[k] = atomicAdd(&cnt[bb[k]], 1);
    }
    __syncthreads();
    if (t < NB) base[t] = t * BCAP + atomicAdd(&gcur[t], cnt[t]);
    __syncthreads();
    #pragma unroll
    for (int k = 0; k < 4; ++k)
        rec[base[bb[k]] + lrank[k]] = prec[k];
}

// ---------------------------------------------------------------------------
// bucket_csr: one block per bucket. LDS deg-count over its 256 nodes -> scan
// -> offS/offE; LDS-cursor scatter of src ids into the bucket's srcS slot.
// ---------------------------------------------------------------------------
__global__ __launch_bounds__(256) void bucket_csr_kernel(
    const unsigned* __restrict__ rec, const int* __restrict__ gcur,
    int* __restrict__ offS, int* __restrict__ offE, int* __restrict__ srcS)
{
    __shared__ int deg[256];
    __shared__ int cur[256];
    __shared__ int lds[256];
    const int t = threadIdx.x, b = blockIdx.x;
    const int r0 = b * BCAP, r1 = r0 + gcur[b], n0 = b << 8;
    deg[t] = 0;
    __syncthreads();
    for (int i = r0 + t; i < r1; i += 256)
        atomicAdd(&deg[rec[i] >> 16], 1);
    __syncthreads();
    const int v = deg[t];
    lds[t] = v;
    __syncthreads();
    for (int s = 1; s < 256; s <<= 1) {
        const int u = (t >= s) ? lds[t - s] : 0;
        __syncthreads();
        lds[t] += u;
        __syncthreads();
    }
    const int excl = r0 + lds[t] - v;
    cur[t] = excl;
    if (n0 + t < N_NODES) { offS[n0 + t] = excl; offE[n0 + t] = excl + v; }
    __syncthreads();
    for (int i = r0 + t; i < r1; i += 256) {
        const unsigned rc = rec[i];
        const int p = atomicAdd(&cur[rc >> 16], 1);
        srcS[p] = (int)(rc & 0xFFFFu);
    }
}

// ---------------------------------------------------------------------------
// Aggregate: ONE NODE PER WAVE (grid*4 == N_NODES), 4 groups x 16 lanes
// (8 ch/lane), depth-2 pipeline (8 edges/iter in flight). No LDS/barriers/
// atomics. Output aggr as bf16 to ws (node_upd rounds to bf16 anyway).
// ---------------------------------------------------------------------------
__global__ __launch_bounds__(256) void aggr_kernel(
    const __bf16* __restrict__ Hsrc, const __bf16* __restrict__ Hdst,
    const float*  __restrict__ pos,  const float* __restrict__ Wmsg,
    const int*    __restrict__ offS, const int*   __restrict__ offE,
    const int*    __restrict__ srcS, __bf16* __restrict__ aggrB)
{
    const int lane = threadIdx.x & 63;
    const int wv   = threadIdx.x >> 6;
    const int g    = lane >> 4;          // edge sub-group 0..3
    const int c8   = (lane & 15) * 8;    // channel base (8 ch/lane)

    float w2[8], hd[8], acc[8];
    *(f32x4*)&w2[0] = *(const f32x4*)(Wmsg + 256 * C + c8);
    *(f32x4*)&w2[4] = *(const f32x4*)(Wmsg + 256 * C + c8 + 4);

    const int n = blockIdx.x * 4 + wv;   // 12500*4 == 50000 exactly
    const int o0 = offS[n], o1 = offE[n];
    {   // unpack Hdst row slice (bf16 -> f32)
        const u32x4 hdb = *(const u32x4*)(Hdst + (long)n * C + c8);
        #pragma unroll
        for (int k = 0; k < 4; ++k) {
            hd[2*k]   = __uint_as_float(hdb[k] << 16);
            hd[2*k+1] = __uint_as_float(hdb[k] & 0xffff0000u);
        }
    }
    const float px = pos[n * 3], py = pos[n * 3 + 1], pz = pos[n * 3 + 2];
    #pragma unroll
    for (int j = 0; j < 8; ++j) acc[j] = 0.f;

    if (o1 > o0) {
        const int last = o1 - 1;
        int s0 = srcS[min(o0 + g,     last)];
        int s1 = srcS[min(o0 + 4 + g, last)];
        for (int e = o0; e < o1; e += 8) {
            // issue both halves' gathers, then prefetch next ids
            const float qx0 = pos[s0*3], qy0 = pos[s0*3+1], qz0 = pos[s0*3+2];
            const u32x4 hu0 = *(const u32x4*)(Hsrc + (long)s0 * C + c8);
            const float qx1 = pos[s1*3], qy1 = pos[s1*3+1], qz1 = pos[s1*3+2];
            const u32x4 hu1 = *(const u32x4*)(Hsrc + (long)s1 * C + c8);
            const int sn0 = srcS[min(e + 8  + g, last)];
            const int sn1 = srcS[min(e + 12 + g, last)];

            {   // half 0: edge e+g
                const float dx = qx0 - px, dy = qy0 - py, dz = qz0 - pz;
                const float d  = dx * dx + dy * dy + dz * dz;
                const bool valid = (e + g) < o1;
                #pragma unroll
                for (int k = 0; k < 4; ++k) {
                    const float flo = __uint_as_float(hu0[k] << 16);
                    const float fhi = __uint_as_float(hu0[k] & 0xffff0000u);
                    const float v0 = fmaxf(flo + hd[2*k]   + d * w2[2*k],   0.f);
                    const float v1 = fmaxf(fhi + hd[2*k+1] + d * w2[2*k+1], 0.f);
                    acc[2*k]   += valid ? v0 : 0.f;
                    acc[2*k+1] += valid ? v1 : 0.f;
                }
            }
            {   // half 1: edge e+4+g
                const float dx = qx1 - px, dy = qy1 - py, dz = qz1 - pz;
                const float d  = dx * dx + dy * dy + dz * dz;
                const bool valid = (e + 4 + g) < o1;
                #pragma unroll
                for (int k = 0; k < 4; ++k) {
                    const float flo = __uint_as_float(hu1[k] << 16);
                    const float fhi = __uint_as_float(hu1[k] & 0xffff0000u);
                    const float v0 = fmaxf(flo + hd[2*k]   + d * w2[2*k],   0.f);
                    const float v1 = fmaxf(fhi + hd[2*k+1] + d * w2[2*k+1], 0.f);
                    acc[2*k]   += valid ? v0 : 0.f;
                    acc[2*k+1] += valid ? v1 : 0.f;
                }
            }
            s0 = sn0; s1 = sn1;
        }
    }
    #pragma unroll
    for (int j = 0; j < 8; ++j) {        // combine the 4 edge groups
        acc[j] += __shfl_xor(acc[j], 16);
        acc[j] += __shfl_xor(acc[j], 32);
    }
    if (lane < 16) {
        bf16x8 v;
        #pragma unroll
        for (int j = 0; j < 8; ++j) v[j] = (__bf16)acc[j];
        *(bf16x8*)(aggrB + (long)n * C + c8) = v;
    }
}

// ---------------------------------------------------------------------------
// Node update: out = embed @ W_res + relu([embed, aggr] @ W_upd + b_upd)
// aggr read as bf16 from ws; out written exactly once.
// ---------------------------------------------------------------------------
__global__ __launch_bounds__(512) void node_upd_kernel(
    const float* __restrict__ embed, const __bf16* __restrict__ aggrB,
    const float* __restrict__ Wres,  const float* __restrict__ Wupd,
    const float* __restrict__ bupd,  float* __restrict__ out)
{
    __shared__ short ldsF[16 * 256];

    const int t = threadIdx.x, lane = t & 63, wave = t >> 6;
    const int chbase = wave * 16, q = lane >> 4, nr = lane & 15;

    bf16x8 aU[8], aR[4];
    {
        const int ch = chbase + nr;
        #pragma unroll
        for (int ks = 0; ks < 8; ++ks)
            #pragma unroll
            for (int i = 0; i < 8; ++i)
                aU[ks][i] = (__bf16)Wupd[(ks*32 + q*8 + i) * C + ch];
        #pragma unroll
        for (int ks = 0; ks < 4; ++ks)
            #pragma unroll
            for (int i = 0; i < 8; ++i)
                aR[ks][i] = (__bf16)Wres[(ks*32 + q*8 + i) * C + ch];
    }
    float bu[4];
    #pragma unroll
    for (int r = 0; r < 4; ++r) bu[r] = bupd[chbase + q*4 + r];

    for (int nt = blockIdx.x; nt < NTILES; nt += gridDim.x) {
        const int n0 = nt * 16;
        {   // stage [embed(f32->bf16) | aggr(bf16 copy)] for 16 nodes
            const int nn = t >> 5, seg = t & 31;
            bf16x8 v;
            if (seg < 16) {
                const float* src = embed + (long)(n0 + nn) * C + seg * 8;
                const float4 f0 = *(const float4*)src;
                const float4 f1 = *(const float4*)(src + 4);
                v[0]=(__bf16)f0.x; v[1]=(__bf16)f0.y; v[2]=(__bf16)f0.z; v[3]=(__bf16)f0.w;
                v[4]=(__bf16)f1.x; v[5]=(__bf16)f1.y; v[6]=(__bf16)f1.z; v[7]=(__bf16)f1.w;
            } else {
                v = *(const bf16x8*)(aggrB + (long)(n0 + nn) * C + (seg & 15) * 8);
            }
            *(bf16x8*)(&ldsF[swz8(nn, seg * 8)]) = v;
        }
        __syncthreads();

        f32x4 au = {0.f,0.f,0.f,0.f}, ar = {0.f,0.f,0.f,0.f};
        #pragma unroll
        for (int ks = 0; ks < 8; ++ks) {
            const bf16x8 b = *(const bf16x8*)(&ldsF[swz8(nr, ks * 32 + q * 8)]);
            au = __builtin_amdgcn_mfma_f32_16x16x32_bf16(aU[ks], b, au, 0, 0, 0);
        }
        #pragma unroll
        for (int ks = 0; ks < 4; ++ks) {
            const bf16x8 b = *(const bf16x8*)(&ldsF[swz8(nr, ks * 32 + q * 8)]);
            ar = __builtin_amdgcn_mfma_f32_16x16x32_bf16(aR[ks], b, ar, 0, 0, 0);
        }
        __syncthreads();

        const int node = n0 + nr;
        float* dst = out + (long)node * C + chbase + q * 4;
        #pragma unroll
        for (int r = 0; r < 4; ++r)
            dst[r] = ar[r] + fmaxf(au[r] + bu[r], 0.f);
    }
}

extern "C" void kernel_launch(void* const* d_in, const int* in_sizes, int n_in,
                              void* d_out, int out_size, void* d_ws, size_t ws_size,
                              hipStream_t stream) {
    const float* embed = (const float*)d_in[0];
    const float* pos   = (const float*)d_in[1];
    const float* Wres  = (const float*)d_in[2];
    const float* Wmsg  = (const float*)d_in[3];
    const float* bmsg  = (const float*)d_in[4];
    const float* Wupd  = (const float*)d_in[5];
    const float* bupd  = (const float*)d_in[6];
    const int*   eidx  = (const int*)d_in[7];
    float* out = (float*)d_out;

    char* ws = (char*)d_ws;
    int*      gcur = (int*)(ws + WS_GCUR);
    int*      offS = (int*)(ws + WS_OFFS);
    int*      offE = (int*)(ws + WS_OFFE);
    int*      srcS = (int*)(ws + WS_SRCS);
    unsigned* rec  = (unsigned*)(ws + WS_REC);
    __bf16*   HdstB= (__bf16*)(ws + WS_HDST);
    __bf16*   Hsrc = (__bf16*)(ws + WS_HSRC);
    __bf16*   aggrB= (__bf16*)(ws + WS_AGGR);

    precomp_kernel<<<1024, 512, 0, stream>>>(embed, Wmsg, bmsg, Hsrc, HdstB, gcur);
    partition_kernel<<<N_EDGES / 1024, 256, 0, stream>>>(eidx, gcur, rec);
    bucket_csr_kernel<<<NB, 256, 0, stream>>>(rec, gcur, offS, offE, srcS);
    aggr_kernel<<<N_NODES / 4, 256, 0, stream>>>(Hsrc, HdstB, pos, Wmsg, offS, offE, srcS, aggrB);
    node_upd_kernel<<<1024, 512, 0, stream>>>(embed, aggrB, Wres, Wupd, bupd, out);
}

// Round 10
// 102.950 us; speedup vs baseline: 1.2884x; 1.0222x over previous
//
#include <hip/hip_runtime.h>
#include <hip/hip_bf16.h>

#define N_NODES 50000
#define N_EDGES 640000
#define C 128            // IN_C == HID
#define NB 196           // dst buckets of 256 nodes (50000 <= 196*256)
#define BCAP 4096        // fixed edge capacity per bucket (mean 3277, +14 sigma)
#define NTILES (N_NODES / 16)                               // 3125

typedef __bf16 bf16x8 __attribute__((ext_vector_type(8)));
typedef __bf16 bf16x4 __attribute__((ext_vector_type(4)));
typedef float  f32x4  __attribute__((ext_vector_type(4)));
typedef float  f32x2  __attribute__((ext_vector_type(2)));
typedef unsigned int u32x4 __attribute__((ext_vector_type(4)));

// ---- d_ws layout (byte offsets) ----
#define WS_GCUR  0          // NB ints (bucket cursors; zeroed by precomp blk0)
#define WS_OFFS  1024       // N ints (per-node edge range start)
#define WS_OFFE  201024     // N ints (per-node edge range end)
#define WS_SRCS  401024     // NB*BCAP ints (src ids, bucketed)
#define WS_REC   3612288    // NB*BCAP u32 packed records
#define WS_HDST  6823552    // N*C bf16 (Hdst + bias)
#define WS_HSRC8 19623552   // N*C fp8 e4m3 (6.4 MB)
#define WS_AGGR  26023552   // N*C bf16 (aggregation result)
// total ~38.8 MB

// XOR-swizzle for [16][128]-short LDS tiles (2-way residual conflict = free).
__device__ __forceinline__ int swzS(int row, int soff) {
    return row * 128 + (soff ^ ((row & 7) << 3));
}
// [16][256]-short variant (node-update staging)
__device__ __forceinline__ int swz8(int row, int soff) {
    return row * 256 + (soff ^ ((row & 7) << 3));
}

// ---------------------------------------------------------------------------
// Precompute Hsrc = embed @ Wmsg[0:128]          (fp8 e4m3, ws)
//            Hdst = embed @ Wmsg[128:256] + b    (bf16, ws)
// Runs FIRST; block 0 also zeroes gcur (stream order covers the dependency).
// ---------------------------------------------------------------------------
__global__ __launch_bounds__(512) void precomp_kernel(
    const float* __restrict__ embed, const float* __restrict__ Wmsg,
    const float* __restrict__ bmsg,  unsigned char* __restrict__ Hsrc8,
    __bf16* __restrict__ Hdst, int* __restrict__ gcur)
{
    __shared__ short lds[16 * 128];

    const int t = threadIdx.x, lane = t & 63, wave = t >> 6;
    const int chbase = wave * 16, q = lane >> 4, nr = lane & 15;
    const int ch = chbase + nr;

    if (blockIdx.x == 0 && t < NB) gcur[t] = 0;

    bf16x8 aS[4], aD[4];
    #pragma unroll
    for (int ks = 0; ks < 4; ++ks)
        #pragma unroll
        for (int i = 0; i < 8; ++i) {
            const int k = ks * 32 + q * 8 + i;
            aS[ks][i] = (__bf16)Wmsg[k * C + ch];
            aD[ks][i] = (__bf16)Wmsg[(128 + k) * C + ch];
        }
    float bias[4];
    #pragma unroll
    for (int r = 0; r < 4; ++r) bias[r] = bmsg[chbase + q * 4 + r];

    for (int nt = blockIdx.x; nt < NTILES; nt += gridDim.x) {
        const int n0 = nt * 16;
        {   // stage 16 nodes x 128 feats: f32 -> bf16 LDS
            const int row = t >> 5, seg = t & 31;
            const float4 f = *(const float4*)(embed + (long)(n0 + row) * C + seg * 4);
            bf16x4 v;
            v[0]=(__bf16)f.x; v[1]=(__bf16)f.y; v[2]=(__bf16)f.z; v[3]=(__bf16)f.w;
            *(bf16x4*)(&lds[swzS(row, seg * 4)]) = v;
        }
        __syncthreads();

        f32x4 hs = {0.f,0.f,0.f,0.f}, hd = {0.f,0.f,0.f,0.f};
        #pragma unroll
        for (int ks = 0; ks < 4; ++ks) {
            const bf16x8 b = *(const bf16x8*)(&lds[swzS(nr, ks * 32 + q * 8)]);
            hs = __builtin_amdgcn_mfma_f32_16x16x32_bf16(aS[ks], b, hs, 0, 0, 0);
            hd = __builtin_amdgcn_mfma_f32_16x16x32_bf16(aD[ks], b, hd, 0, 0, 0);
        }
        __syncthreads();

        const int node = n0 + nr;            // D: col=node, row(q*4+r)=ch
        // Hsrc -> fp8 e4m3 packed (byte r <-> channel chbase+q*4+r)
        int w8 = 0;
        w8 = __builtin_amdgcn_cvt_pk_fp8_f32(hs[0], hs[1], w8, false);
        w8 = __builtin_amdgcn_cvt_pk_fp8_f32(hs[2], hs[3], w8, true);
        *(unsigned*)(Hsrc8 + (long)node * C + chbase + q * 4) = (unsigned)w8;
        bf16x4 vd;
        #pragma unroll
        for (int r = 0; r < 4; ++r) vd[r] = (__bf16)(hd[r] + bias[r]);
        *(bf16x4*)(Hdst + (long)node * C + chbase + q * 4) = vd;
    }
}

// ---------------------------------------------------------------------------
// partition: bin 1024 edges/block by dst>>8 via LDS counters; reserve a range
// in the bucket's FIXED slot [b*BCAP, (b+1)*BCAP) with one global atomic per
// bucket per block; write packed 4B records (src | dstLocal<<16).
// ---------------------------------------------------------------------------
__global__ __launch_bounds__(256) void partition_kernel(
    const int* __restrict__ eidx, int* __restrict__ gcur,
    unsigned* __restrict__ rec)
{
    __shared__ int cnt[NB];
    __shared__ int base[NB];
    const int t = threadIdx.x;
    if (t < NB) cnt[t] = 0;
    __syncthreads();
    const int e0 = blockIdx.x * 1024;
    int lrank[4], bb[4];
    unsigned prec[4];
    #pragma unroll
    for (int k = 0; k < 4; ++k) {
        const int e = e0 + k * 256 + t;
        const int r = eidx[e], c = eidx[N_EDGES + e];
        bb[k]   = c >> 8;
        prec[k] = (unsigned)r | ((unsigned)(c & 255) << 16);
        lrank[k] = atomicAdd(&cnt[bb[k]], 1);
    }
    __syncthreads();
    if (t < NB) base[t] = t * BCAP + atomicAdd(&gcur[t], cnt[t]);
    __syncthreads();
    #pragma unroll
    for (int k = 0; k < 4; ++k)
        rec[base[bb[k]] + lrank[k]] = prec[k];
}

// ---------------------------------------------------------------------------
// bucket_csr: one block per bucket. LDS deg-count over its 256 nodes -> scan
// -> offS/offE; LDS-cursor scatter of src ids into the bucket's srcS slot.
// ---------------------------------------------------------------------------
__global__ __launch_bounds__(256) void bucket_csr_kernel(
    const unsigned* __restrict__ rec, const int* __restrict__ gcur,
    int* __restrict__ offS, int* __restrict__ offE, int* __restrict__ srcS)
{
    __shared__ int deg[256];
    __shared__ int cur[256];
    __shared__ int lds[256];
    const int t = threadIdx.x, b = blockIdx.x;
    const int r0 = b * BCAP, r1 = r0 + gcur[b], n0 = b << 8;
    deg[t] = 0;
    __syncthreads();
    for (int i = r0 + t; i < r1; i += 256)
        atomicAdd(&deg[rec[i] >> 16], 1);
    __syncthreads();
    const int v = deg[t];
    lds[t] = v;
    __syncthreads();
    for (int s = 1; s < 256; s <<= 1) {
        const int u = (t >= s) ? lds[t - s] : 0;
        __syncthreads();
        lds[t] += u;
        __syncthreads();
    }
    const int excl = r0 + lds[t] - v;
    cur[t] = excl;
    if (n0 + t < N_NODES) { offS[n0 + t] = excl; offE[n0 + t] = excl + v; }
    __syncthreads();
    for (int i = r0 + t; i < r1; i += 256) {
        const unsigned rc = rec[i];
        const int p = atomicAdd(&cur[rc >> 16], 1);
        srcS[p] = (int)(rc & 0xFFFFu);
    }
}

// ---------------------------------------------------------------------------
// Aggregate: ONE NODE PER WAVE (grid*4 == N_NODES), 4 groups x 16 lanes
// (8 ch/lane), depth-2 pipeline (8 edges/iter in flight). Hsrc gathered as
// fp8 e4m3 (8B/lane/edge) and decoded with v_cvt_pk_f32_fp8. No LDS/barriers/
// atomics. Output aggr as bf16 to ws.
// ---------------------------------------------------------------------------
__global__ __launch_bounds__(256) void aggr_kernel(
    const unsigned char* __restrict__ Hsrc8, const __bf16* __restrict__ Hdst,
    const float*  __restrict__ pos,  const float* __restrict__ Wmsg,
    const int*    __restrict__ offS, const int*   __restrict__ offE,
    const int*    __restrict__ srcS, __bf16* __restrict__ aggrB)
{
    const int lane = threadIdx.x & 63;
    const int wv   = threadIdx.x >> 6;
    const int g    = lane >> 4;          // edge sub-group 0..3
    const int c8   = (lane & 15) * 8;    // channel base (8 ch/lane)

    float w2[8], hd[8], acc[8];
    *(f32x4*)&w2[0] = *(const f32x4*)(Wmsg + 256 * C + c8);
    *(f32x4*)&w2[4] = *(const f32x4*)(Wmsg + 256 * C + c8 + 4);

    const int n = blockIdx.x * 4 + wv;   // 12500*4 == 50000 exactly
    const int o0 = offS[n], o1 = offE[n];
    {   // unpack Hdst row slice (bf16 -> f32)
        const u32x4 hdb = *(const u32x4*)(Hdst + (long)n * C + c8);
        #pragma unroll
        for (int k = 0; k < 4; ++k) {
            hd[2*k]   = __uint_as_float(hdb[k] << 16);
            hd[2*k+1] = __uint_as_float(hdb[k] & 0xffff0000u);
        }
    }
    const float px = pos[n * 3], py = pos[n * 3 + 1], pz = pos[n * 3 + 2];
    #pragma unroll
    for (int j = 0; j < 8; ++j) acc[j] = 0.f;

    if (o1 > o0) {
        const int last = o1 - 1;
        int s0 = srcS[min(o0 + g,     last)];
        int s1 = srcS[min(o0 + 4 + g, last)];
        for (int e = o0; e < o1; e += 8) {
            // issue both halves' gathers, then prefetch next ids
            const float qx0 = pos[s0*3], qy0 = pos[s0*3+1], qz0 = pos[s0*3+2];
            const uint2 hu0 = *(const uint2*)(Hsrc8 + (long)s0 * C + c8);
            const float qx1 = pos[s1*3], qy1 = pos[s1*3+1], qz1 = pos[s1*3+2];
            const uint2 hu1 = *(const uint2*)(Hsrc8 + (long)s1 * C + c8);
            const int sn0 = srcS[min(e + 8  + g, last)];
            const int sn1 = srcS[min(e + 12 + g, last)];

            {   // half 0: edge e+g
                const float dx = qx0 - px, dy = qy0 - py, dz = qz0 - pz;
                const float d  = dx * dx + dy * dy + dz * dz;
                const bool valid = (e + g) < o1;
                const f32x2 p0 = __builtin_amdgcn_cvt_pk_f32_fp8((int)hu0.x, false);
                const f32x2 p1 = __builtin_amdgcn_cvt_pk_f32_fp8((int)hu0.x, true);
                const f32x2 p2 = __builtin_amdgcn_cvt_pk_f32_fp8((int)hu0.y, false);
                const f32x2 p3 = __builtin_amdgcn_cvt_pk_f32_fp8((int)hu0.y, true);
                const float hs[8] = {p0[0],p0[1],p1[0],p1[1],p2[0],p2[1],p3[0],p3[1]};
                #pragma unroll
                for (int j = 0; j < 8; ++j) {
                    const float v = fmaxf(hs[j] + hd[j] + d * w2[j], 0.f);
                    acc[j] += valid ? v : 0.f;
                }
            }
            {   // half 1: edge e+4+g
                const float dx = qx1 - px, dy = qy1 - py, dz = qz1 - pz;
                const float d  = dx * dx + dy * dy + dz * dz;
                const bool valid = (e + 4 + g) < o1;
                const f32x2 p0 = __builtin_amdgcn_cvt_pk_f32_fp8((int)hu1.x, false);
                const f32x2 p1 = __builtin_amdgcn_cvt_pk_f32_fp8((int)hu1.x, true);
                const f32x2 p2 = __builtin_amdgcn_cvt_pk_f32_fp8((int)hu1.y, false);
                const f32x2 p3 = __builtin_amdgcn_cvt_pk_f32_fp8((int)hu1.y, true);
                const float hs[8] = {p0[0],p0[1],p1[0],p1[1],p2[0],p2[1],p3[0],p3[1]};
                #pragma unroll
                for (int j = 0; j < 8; ++j) {
                    const float v = fmaxf(hs[j] + hd[j] + d * w2[j], 0.f);
                    acc[j] += valid ? v : 0.f;
                }
            }
            s0 = sn0; s1 = sn1;
        }
    }
    #pragma unroll
    for (int j = 0; j < 8; ++j) {        // combine the 4 edge groups
        acc[j] += __shfl_xor(acc[j], 16);
        acc[j] += __shfl_xor(acc[j], 32);
    }
    if (lane < 16) {
        bf16x8 v;
        #pragma unroll
        for (int j = 0; j < 8; ++j) v[j] = (__bf16)acc[j];
        *(bf16x8*)(aggrB + (long)n * C + c8) = v;
    }
}

// ---------------------------------------------------------------------------
// Node update: out = embed @ W_res + relu([embed, aggr] @ W_upd + b_upd)
// aggr read as bf16 from ws; out written exactly once.
// ---------------------------------------------------------------------------
__global__ __launch_bounds__(512) void node_upd_kernel(
    const float* __restrict__ embed, const __bf16* __restrict__ aggrB,
    const float* __restrict__ Wres,  const float* __restrict__ Wupd,
    const float* __restrict__ bupd,  float* __restrict__ out)
{
    __shared__ short ldsF[16 * 256];

    const int t = threadIdx.x, lane = t & 63, wave = t >> 6;
    const int chbase = wave * 16, q = lane >> 4, nr = lane & 15;

    bf16x8 aU[8], aR[4];
    {
        const int ch = chbase + nr;
        #pragma unroll
        for (int ks = 0; ks < 8; ++ks)
            #pragma unroll
            for (int i = 0; i < 8; ++i)
                aU[ks][i] = (__bf16)Wupd[(ks*32 + q*8 + i) * C + ch];
        #pragma unroll
        for (int ks = 0; ks < 4; ++ks)
            #pragma unroll
            for (int i = 0; i < 8; ++i)
                aR[ks][i] = (__bf16)Wres[(ks*32 + q*8 + i) * C + ch];
    }
    float bu[4];
    #pragma unroll
    for (int r = 0; r < 4; ++r) bu[r] = bupd[chbase + q*4 + r];

    for (int nt = blockIdx.x; nt < NTILES; nt += gridDim.x) {
        const int n0 = nt * 16;
        {   // stage [embed(f32->bf16) | aggr(bf16 copy)] for 16 nodes
            const int nn = t >> 5, seg = t & 31;
            bf16x8 v;
            if (seg < 16) {
                const float* src = embed + (long)(n0 + nn) * C + seg * 8;
                const float4 f0 = *(const float4*)src;
                const float4 f1 = *(const float4*)(src + 4);
                v[0]=(__bf16)f0.x; v[1]=(__bf16)f0.y; v[2]=(__bf16)f0.z; v[3]=(__bf16)f0.w;
                v[4]=(__bf16)f1.x; v[5]=(__bf16)f1.y; v[6]=(__bf16)f1.z; v[7]=(__bf16)f1.w;
            } else {
                v = *(const bf16x8*)(aggrB + (long)(n0 + nn) * C + (seg & 15) * 8);
            }
            *(bf16x8*)(&ldsF[swz8(nn, seg * 8)]) = v;
        }
        __syncthreads();

        f32x4 au = {0.f,0.f,0.f,0.f}, ar = {0.f,0.f,0.f,0.f};
        #pragma unroll
        for (int ks = 0; ks < 8; ++ks) {
            const bf16x8 b = *(const bf16x8*)(&ldsF[swz8(nr, ks * 32 + q * 8)]);
            au = __builtin_amdgcn_mfma_f32_16x16x32_bf16(aU[ks], b, au, 0, 0, 0);
        }
        #pragma unroll
        for (int ks = 0; ks < 4; ++ks) {
            const bf16x8 b = *(const bf16x8*)(&ldsF[swz8(nr, ks * 32 + q * 8)]);
            ar = __builtin_amdgcn_mfma_f32_16x16x32_bf16(aR[ks], b, ar, 0, 0, 0);
        }
        __syncthreads();

        const int node = n0 + nr;
        float* dst = out + (long)node * C + chbase + q * 4;
        #pragma unroll
        for (int r = 0; r < 4; ++r)
            dst[r] = ar[r] + fmaxf(au[r] + bu[r], 0.f);
    }
}

extern "C" void kernel_launch(void* const* d_in, const int* in_sizes, int n_in,
                              void* d_out, int out_size, void* d_ws, size_t ws_size,
                              hipStream_t stream) {
    const float* embed = (const float*)d_in[0];
    const float* pos   = (const float*)d_in[1];
    const float* Wres  = (const float*)d_in[2];
    const float* Wmsg  = (const float*)d_in[3];
    const float* bmsg  = (const float*)d_in[4];
    const float* Wupd  = (const float*)d_in[5];
    const float* bupd  = (const float*)d_in[6];
    const int*   eidx  = (const int*)d_in[7];
    float* out = (float*)d_out;

    char* ws = (char*)d_ws;
    int*            gcur  = (int*)(ws + WS_GCUR);
    int*            offS  = (int*)(ws + WS_OFFS);
    int*            offE  = (int*)(ws + WS_OFFE);
    int*            srcS  = (int*)(ws + WS_SRCS);
    unsigned*       rec   = (unsigned*)(ws + WS_REC);
    __bf16*         HdstB = (__bf16*)(ws + WS_HDST);
    unsigned char*  Hsrc8 = (unsigned char*)(ws + WS_HSRC8);
    __bf16*         aggrB = (__bf16*)(ws + WS_AGGR);

    precomp_kernel<<<1024, 512, 0, stream>>>(embed, Wmsg, bmsg, Hsrc8, HdstB, gcur);
    partition_kernel<<<N_EDGES / 1024, 256, 0, stream>>>(eidx, gcur, rec);
    bucket_csr_kernel<<<NB, 256, 0, stream>>>(rec, gcur, offS, offE, srcS);
    aggr_kernel<<<N_NODES / 4, 256, 0, stream>>>(Hsrc8, HdstB, pos, Wmsg, offS, offE, srcS, aggrB);
    node_upd_kernel<<<1024, 512, 0, stream>>>(embed, aggrB, Wres, Wupd, bupd, out);
}